// Round 2
// baseline (386.843 us; speedup 1.0000x reference)
//
#include <hip/hip_runtime.h>
#include <hip/hip_bf16.h>

// GAT attention head, N=8192, F_IN=256, OUT=64, bias_mat [N,N] f32.
// kA: fts = seq@W1 (bf16 MFMA), f1/f2 rank-1 terms, ftsT bf16 for PV B-frags.
// kB v2: flash-style online softmax over the 256MB bias stream (HBM roofline).
//   512 blocks x 16 q-rows, 512 thr (8 waves, 8-way j-split), round = 256 j.
//   Bias: 2-round-deep register prefetch -> single LDS buffer (barrier-
//   separated phases). ftsT/f2: L2-resident, direct-to-reg, 2 rounds ahead.
//   Defer-max rescale (T13, THR=8). P stays in MFMA A-fragment layout.

typedef float f32x4 __attribute__((ext_vector_type(4)));
typedef short bf16x8 __attribute__((ext_vector_type(8)));

__device__ __forceinline__ unsigned short f2bf(float x) {
    union { float f; unsigned u; } v; v.f = x;
    unsigned r = v.u + 0x7FFF + ((v.u >> 16) & 1);   // RNE
    return (unsigned short)(r >> 16);
}

__device__ __forceinline__ float elu1(float x) {
    return x > 0.f ? x : (__expf(x) - 1.f);
}

// ---------------- kernel A: fts, f1, f2, ftsT ----------------
// grid 256, block 256 (4 waves). Block handles 32 q-rows.
__global__ __launch_bounds__(256) void attn_fts(
    const float* __restrict__ seq, const float* __restrict__ W1,
    const float* __restrict__ a1, const float* __restrict__ b1,
    const float* __restrict__ a2, const float* __restrict__ b2,
    unsigned short* __restrict__ ftsT, float* __restrict__ f1g,
    float* __restrict__ f2g)
{
    __shared__ unsigned short w1t[64 * 264];      // W1^T bf16, 528B rows
    __shared__ unsigned short stage[64 * 40];     // ftsT staging [64 o][32 q +8]
    __shared__ float f1p[2][32];
    __shared__ float f2p[2][32];

    const int tid = threadIdx.x;
    const int qb = blockIdx.x * 32;
    const int w = tid >> 6, rg = w & 1, oh = w >> 1;
    const int lane = tid & 63, c = lane & 15, g = lane >> 4;

    for (int i = 0; i < 64; ++i) {
        int e = tid + i * 256;            // e = k*64 + o
        int k = e >> 6, o = e & 63;
        w1t[o * 264 + k] = f2bf(W1[e]);
    }
    __syncthreads();

    f32x4 acc[2] = {};
    const float* srow = seq + (long)(qb + rg * 16 + c) * 256;
    #pragma unroll
    for (int ks = 0; ks < 8; ++ks) {
        int k0 = ks * 32 + g * 8;
        float4 s0 = *(const float4*)(srow + k0);
        float4 s1 = *(const float4*)(srow + k0 + 4);
        bf16x8 af;
        af[0] = (short)f2bf(s0.x); af[1] = (short)f2bf(s0.y);
        af[2] = (short)f2bf(s0.z); af[3] = (short)f2bf(s0.w);
        af[4] = (short)f2bf(s1.x); af[5] = (short)f2bf(s1.y);
        af[6] = (short)f2bf(s1.z); af[7] = (short)f2bf(s1.w);
        #pragma unroll
        for (int ob = 0; ob < 2; ++ob) {
            int brow = oh * 32 + ob * 16 + c;
            bf16x8 bf = *(const bf16x8*)(&w1t[brow * 264 + k0]);
            acc[ob] = __builtin_amdgcn_mfma_f32_16x16x32_bf16(af, bf, acc[ob], 0, 0, 0);
        }
    }

    float a1v0 = a1[oh * 32 + c], a1v1 = a1[oh * 32 + 16 + c];
    float a2v0 = a2[oh * 32 + c], a2v1 = a2[oh * 32 + 16 + c];
    #pragma unroll
    for (int reg = 0; reg < 4; ++reg) {
        float p1 = acc[0][reg] * a1v0 + acc[1][reg] * a1v1;
        float p2 = acc[0][reg] * a2v0 + acc[1][reg] * a2v1;
        #pragma unroll
        for (int mm = 1; mm < 16; mm <<= 1) {
            p1 += __shfl_xor(p1, mm, 64);
            p2 += __shfl_xor(p2, mm, 64);
        }
        if (c == 0) {
            f1p[oh][rg * 16 + g * 4 + reg] = p1;
            f2p[oh][rg * 16 + g * 4 + reg] = p2;
        }
    }

    #pragma unroll
    for (int ob = 0; ob < 2; ++ob) {
        int row = oh * 32 + ob * 16 + c;
        #pragma unroll
        for (int rp = 0; rp < 2; ++rp) {
            unsigned short lo = f2bf(acc[ob][rp * 2]);
            unsigned short hi = f2bf(acc[ob][rp * 2 + 1]);
            unsigned v = (unsigned)lo | ((unsigned)hi << 16);
            *(unsigned*)(&stage[row * 40 + rg * 16 + g * 4 + rp * 2]) = v;
        }
    }
    __syncthreads();

    {
        int o = tid >> 2, q4 = tid & 3;
        uint4 v = *(const uint4*)(&stage[o * 40 + q4 * 8]);
        *(uint4*)(&ftsT[(long)o * 8192 + qb + q4 * 8]) = v;
    }
    if (tid < 32) {
        f1g[qb + tid] = f1p[0][tid] + f1p[1][tid] + b1[0];
        f2g[qb + tid] = f2p[0][tid] + f2p[1][tid] + b2[0];
    }
}

// ---------------- kernel B v2 ----------------
__global__ __launch_bounds__(512, 4) void attn_main(
    const float* __restrict__ bias, const unsigned short* __restrict__ ftsT,
    const float* __restrict__ f1g, const float* __restrict__ f2g,
    float* __restrict__ out)
{
    __shared__ float bias_lds[16][260];      // 16.6 KB, 1040B rows (8 bank classes)
    __shared__ float macc[8][16][68];        // 34.8 KB merge area
    __shared__ float mlm[8][16];
    __shared__ float mll[8][16];

    const int tid = threadIdx.x;
    const int qb = blockIdx.x * 16;
    const int h = tid >> 6;                   // wave = j-split 0..7
    const int lane = tid & 63, c = lane & 15, g = lane >> 4;

    // staging roles: 512 thr cover 16 rows x 256 cols (32B/thread)
    const int srow = tid >> 5, schunk = tid & 31;
    const float* bias_base = bias + (long)(qb + srow) * 8192 + schunk * 8;

    const float f1r = f1g[qb + c];
    // B-fragment source: fts rows ob*16+c, cols j0 + h*32 + g*8 .. +8
    const unsigned short* fts_base = ftsT + (long)c * 8192 + h * 32 + g * 8;
    const float* f2_base = f2g + h * 32 + g * 8;

    float4 bA0, bA1, bB0, bB1;
    bf16x8 fA0, fA1, fA2, fA3, fB0, fB1, fB2, fB3;
    float4 f2Aa, f2Ab, f2Ba, f2Bb;

    auto issue_biasA = [&](int r) {
        const float* p = bias_base + r * 256;
        bA0 = ((const float4*)p)[0]; bA1 = ((const float4*)p)[1];
    };
    auto issue_biasB = [&](int r) {
        const float* p = bias_base + r * 256;
        bB0 = ((const float4*)p)[0]; bB1 = ((const float4*)p)[1];
    };
    auto issue_ftsA = [&](int r) {
        const unsigned short* p = fts_base + r * 256;
        fA0 = *(const bf16x8*)(p);
        fA1 = *(const bf16x8*)(p + 16 * 8192);
        fA2 = *(const bf16x8*)(p + 32 * 8192);
        fA3 = *(const bf16x8*)(p + 48 * 8192);
        const float* q = f2_base + r * 256;
        f2Aa = ((const float4*)q)[0]; f2Ab = ((const float4*)q)[1];
    };
    auto issue_ftsB = [&](int r) {
        const unsigned short* p = fts_base + r * 256;
        fB0 = *(const bf16x8*)(p);
        fB1 = *(const bf16x8*)(p + 16 * 8192);
        fB2 = *(const bf16x8*)(p + 32 * 8192);
        fB3 = *(const bf16x8*)(p + 48 * 8192);
        const float* q = f2_base + r * 256;
        f2Ba = ((const float4*)q)[0]; f2Bb = ((const float4*)q)[1];
    };

    float m = -INFINITY, lsum = 0.f;
    f32x4 acc[4] = {};

    auto do_round = [&](const bf16x8& ff0, const bf16x8& ff1,
                        const bf16x8& ff2, const bf16x8& ff3,
                        const float4& fa, const float4& fb) {
        float4 s0v = *(const float4*)(&bias_lds[c][h * 32 + g * 8]);
        float4 s1v = *(const float4*)(&bias_lds[c][h * 32 + g * 8 + 4]);
        float bb[8] = { s0v.x, s0v.y, s0v.z, s0v.w, s1v.x, s1v.y, s1v.z, s1v.w };
        float f2v[8] = { fa.x, fa.y, fa.z, fa.w, fb.x, fb.y, fb.z, fb.w };
        float s[8];
        float tm = -INFINITY;
        #pragma unroll
        for (int i = 0; i < 8; ++i) {
            float z = f1r + f2v[i];
            z = fmaxf(z, 0.2f * z);               // leaky_relu(0.2)
            float sv = z + bb[i];
            s[i] = sv;
            tm = fmaxf(tm, sv);
        }
        tm = fmaxf(tm, __shfl_xor(tm, 16, 64));
        tm = fmaxf(tm, __shfl_xor(tm, 32, 64));
        if (!__all(tm <= m + 8.f)) {              // defer-max (T13)
            float mnew = fmaxf(m, tm);
            float sc = __expf(m - mnew);
            lsum *= sc;
            float scq[4];
            #pragma unroll
            for (int reg = 0; reg < 4; ++reg) scq[reg] = __shfl(sc, g * 4 + reg, 64);
            #pragma unroll
            for (int ob = 0; ob < 4; ++ob)
                #pragma unroll
                for (int reg = 0; reg < 4; ++reg) acc[ob][reg] *= scq[reg];
            m = mnew;
        }
        float ts = 0.f;
        bf16x8 af;
        #pragma unroll
        for (int i = 0; i < 8; ++i) {
            float p = __expf(s[i] - m);           // bounded by e^8 when deferred
            ts += p;
            af[i] = (short)f2bf(p);
        }
        ts += __shfl_xor(ts, 16, 64);
        ts += __shfl_xor(ts, 32, 64);
        lsum += ts;
        acc[0] = __builtin_amdgcn_mfma_f32_16x16x32_bf16(af, ff0, acc[0], 0, 0, 0);
        acc[1] = __builtin_amdgcn_mfma_f32_16x16x32_bf16(af, ff1, acc[1], 0, 0, 0);
        acc[2] = __builtin_amdgcn_mfma_f32_16x16x32_bf16(af, ff2, acc[2], 0, 0, 0);
        acc[3] = __builtin_amdgcn_mfma_f32_16x16x32_bf16(af, ff3, acc[3], 0, 0, 0);
    };

    // prologue: 2-deep prefetch
    issue_biasA(0); issue_ftsA(0);
    issue_biasB(1); issue_ftsB(1);

    #pragma unroll 1
    for (int rp = 0; rp < 16; ++rp) {
        // ---- round 2*rp (A) ----
        __syncthreads();
        *(float4*)(&bias_lds[srow][schunk * 8]) = bA0;
        *(float4*)(&bias_lds[srow][schunk * 8 + 4]) = bA1;
        if (rp < 15) issue_biasA(2 * rp + 2);
        __syncthreads();
        do_round(fA0, fA1, fA2, fA3, f2Aa, f2Ab);
        if (rp < 15) issue_ftsA(2 * rp + 2);
        // ---- round 2*rp+1 (B) ----
        __syncthreads();
        *(float4*)(&bias_lds[srow][schunk * 8]) = bB0;
        *(float4*)(&bias_lds[srow][schunk * 8 + 4]) = bB1;
        if (rp < 15) issue_biasB(2 * rp + 3);
        __syncthreads();
        do_round(fB0, fB1, fB2, fB3, f2Ba, f2Bb);
        if (rp < 15) issue_ftsB(2 * rp + 3);
    }

    __syncthreads();
    #pragma unroll
    for (int ob = 0; ob < 4; ++ob)
        #pragma unroll
        for (int reg = 0; reg < 4; ++reg)
            macc[h][g * 4 + reg][ob * 16 + c] = acc[ob][reg];
    if (lane < 16) { mlm[h][c] = m; mll[h][c] = lsum; }
    __syncthreads();

    // merge 8 j-splits, normalize, elu, store: 256 thr x 4 outputs
    if (tid < 256) {
        const int row = tid >> 4;            // 0..15
        const int o0 = (tid & 15) * 4;
        float ms = -INFINITY;
        #pragma unroll
        for (int sI = 0; sI < 8; ++sI) ms = fmaxf(ms, mlm[sI][row]);
        float den = 0.f;
        float vx = 0.f, vy = 0.f, vz = 0.f, vw = 0.f;
        #pragma unroll
        for (int sI = 0; sI < 8; ++sI) {
            float ws = __expf(mlm[sI][row] - ms);
            den += mll[sI][row] * ws;
            float4 a = *(const float4*)(&macc[sI][row][o0]);
            vx += a.x * ws; vy += a.y * ws; vz += a.z * ws; vw += a.w * ws;
        }
        float inv = 1.f / den;
        float4 res;
        res.x = elu1(vx * inv); res.y = elu1(vy * inv);
        res.z = elu1(vz * inv); res.w = elu1(vw * inv);
        *(float4*)(&out[(long)(qb + row) * 64 + o0]) = res;
    }
}

extern "C" void kernel_launch(void* const* d_in, const int* in_sizes, int n_in,
                              void* d_out, int out_size, void* d_ws, size_t ws_size,
                              hipStream_t stream) {
    (void)in_sizes; (void)n_in; (void)out_size; (void)ws_size;
    const float* seq  = (const float*)d_in[0];
    const float* bias = (const float*)d_in[1];
    const float* W1   = (const float*)d_in[2];
    const float* a1   = (const float*)d_in[3];
    const float* b1   = (const float*)d_in[4];
    const float* a2   = (const float*)d_in[5];
    const float* b2   = (const float*)d_in[6];
    float* out = (float*)d_out;

    unsigned short* ftsT = (unsigned short*)d_ws;                      // 1 MB
    float* f1 = (float*)((char*)d_ws + 64 * 8192 * 2);                 // 32 KB
    float* f2 = (float*)((char*)d_ws + 64 * 8192 * 2 + 8192 * 4);      // 32 KB

    hipLaunchKernelGGL(attn_fts, dim3(256), dim3(256), 0, stream,
                       seq, W1, a1, b1, a2, b2, ftsT, f1, f2);
    hipLaunchKernelGGL(attn_main, dim3(512), dim3(512), 0, stream,
                       bias, ftsT, f1, f2, out);
}